// Round 15
// baseline (306.216 us; speedup 1.0000x reference)
//
#include <hip/hip_runtime.h>
#include <hip/hip_bf16.h>
#include <cstdint>

// ---------------------------------------------------------------------------
// GCN 3-layer forward. fp32 SpMM, bf16x3 split-MFMA GEMMs (layers 1-2).
// Round 15: SpMM = wave-per-node, lane = 2 cols, 8-edge unroll into 8
// independent accumulator slots -> 8 gathers/lane structurally in flight
// (r13/r14: compiler kept collapsing stream/prefetch forms to ~4 edges,
// VGPR=36; FETCH=177MB is the compulsory floor, MLP is the only lever).
// ---------------------------------------------------------------------------

#define F_IN 256
#define HDIM 128
#define CDIM 40
#define RBITS 13
#define RSIZE 8192
#define NSUB 64

typedef short bf16x8 __attribute__((ext_vector_type(8)));
typedef float f32x4  __attribute__((ext_vector_type(4)));

__device__ __forceinline__ ushort f2bf(float x) {
    uint b = __float_as_uint(x);
    return (ushort)((b + 0x7fffu + ((b >> 16) & 1u)) >> 16);   // RNE
}
__device__ __forceinline__ float bf2f(ushort h) {
    return __uint_as_float(((uint)h) << 16);
}

// ---- stage 1: per-(range,subset) LDS histogram, packed in|out --------------
__global__ __launch_bounds__(256)
void histo_range(const int* __restrict__ src, const int* __restrict__ dst,
                 int* __restrict__ pc, int E) {
    __shared__ int h[RSIZE];
    const int s = blockIdx.x;
    const int r = blockIdx.y;
    const int base = r << RBITS;
    const int t = threadIdx.x;
    int4* h4 = reinterpret_cast<int4*>(h);
    for (int j = t; j < RSIZE / 4; j += 256) h4[j] = make_int4(0, 0, 0, 0);
    __syncthreads();

    const int ech = (E + NSUB - 1) / NSUB;
    const int e0 = s * ech;
    const int e1 = min(E, e0 + ech);
    const int n4 = (e1 - e0) >> 2;
    for (int g = t; g < n4; g += 256) {
        int4 d4 = *reinterpret_cast<const int4*>(dst + e0 + g * 4);
        int4 s4 = *reinterpret_cast<const int4*>(src + e0 + g * 4);
        #pragma unroll
        for (int j = 0; j < 4; ++j) {
            int d = (&d4.x)[j] - base;
            int v = (&s4.x)[j] - base;
            if ((unsigned)d < RSIZE) atomicAdd(&h[d], 1);
            if ((unsigned)v < RSIZE) atomicAdd(&h[v], 0x10000);
        }
    }
    for (int e = e0 + n4 * 4 + t; e < e1; e += 256) {
        int d = dst[e] - base, v = src[e] - base;
        if ((unsigned)d < RSIZE) atomicAdd(&h[d], 1);
        if ((unsigned)v < RSIZE) atomicAdd(&h[v], 0x10000);
    }
    __syncthreads();
    int* p = pc + ((size_t)r * NSUB + s) * RSIZE;
    for (int j = t; j < RSIZE; j += 256) p[j] = h[j];
}

// ---- stage 2: block-level exclusive scan of in-degree ----------------------
__global__ __launch_bounds__(256)
void scan_blocks(const int* __restrict__ pc, int* __restrict__ out,
                 int* __restrict__ bsums, int n) {
    const int t = threadIdx.x;
    const int idx = blockIdx.x * 1024 + t * 4;
    int4 v = make_int4(0, 0, 0, 0);
    if (idx + 3 < n) {
        const int r = idx >> RBITS, off = idx & (RSIZE - 1);
        const int* p = pc + (size_t)r * NSUB * RSIZE + off;
        #pragma unroll 8
        for (int c = 0; c < NSUB; ++c) {
            int4 u = *reinterpret_cast<const int4*>(p + (size_t)c * RSIZE);
            v.x += u.x & 0xffff; v.y += u.y & 0xffff;
            v.z += u.z & 0xffff; v.w += u.w & 0xffff;
        }
    } else {
        for (int j = 0; j < 4; ++j) {
            if (idx + j < n) {
                const int r = (idx + j) >> RBITS, off = (idx + j) & (RSIZE - 1);
                int s = 0;
                for (int c = 0; c < NSUB; ++c)
                    s += pc[(size_t)r * NSUB * RSIZE + (size_t)c * RSIZE + off] & 0xffff;
                (&v.x)[j] = s;
            }
        }
    }
    const int s = v.x + v.y + v.z + v.w;
    const int lane = t & 63;
    int incl = s;
    #pragma unroll
    for (int off = 1; off < 64; off <<= 1) {
        int u = __shfl_up(incl, off);
        if (lane >= off) incl += u;
    }
    __shared__ int wsum[4];
    if (lane == 63) wsum[t >> 6] = incl;
    __syncthreads();
    const int w = t >> 6;
    int woff = 0;
    if (w > 0) woff += wsum[0];
    if (w > 1) woff += wsum[1];
    if (w > 2) woff += wsum[2];
    const int excl = woff + incl - s;
    if (idx + 3 < n) {
        *reinterpret_cast<int4*>(out + idx) =
            make_int4(excl, excl + v.x, excl + v.x + v.y, excl + v.x + v.y + v.z);
    } else {
        if (idx     < n) out[idx]     = excl;
        if (idx + 1 < n) out[idx + 1] = excl + v.x;
        if (idx + 2 < n) out[idx + 2] = excl + v.x + v.y;
        if (idx + 3 < n) out[idx + 3] = excl + v.x + v.y + v.z;
    }
    if (t == 255) bsums[blockIdx.x] = woff + incl;
}

__global__ __launch_bounds__(64)
void scan_sums(int* __restrict__ bsums, int nb) {
    const int lane = threadIdx.x & 63;
    int carry = 0;
    for (int base = 0; base < nb; base += 64) {
        int v = (base + lane < nb) ? bsums[base + lane] : 0;
        int incl = v;
        #pragma unroll
        for (int off = 1; off < 64; off <<= 1) {
            int u = __shfl_up(incl, off);
            if (lane >= off) incl += u;
        }
        if (base + lane < nb) bsums[base + lane] = carry + incl - v;
        carry += __shfl(incl, 63);
    }
}

// ---- stage 3: finalize row_ptr, norms, per-subset cursor bases cb ----------
__global__ __launch_bounds__(256)
void node_prep_kernel(const int* __restrict__ pc,
                      int* __restrict__ row_ptr, const int* __restrict__ bsums,
                      float* __restrict__ out_norm, float* __restrict__ in_norm,
                      int* __restrict__ cb, int n, int E) {
    int i = blockIdx.x * 256 + threadIdx.x;
    if (i < n) {
        const int r = i >> RBITS, off = i & (RSIZE - 1);
        const int* p = pc + (size_t)r * NSUB * RSIZE + off;
        int rp = row_ptr[i] + bsums[i >> 10];
        row_ptr[i] = rp;
        int cur = rp;
        int od = 0;
        #pragma unroll 8
        for (int c = 0; c < NSUB; ++c) {
            unsigned pv = (unsigned)p[(size_t)c * RSIZE];
            cb[(size_t)c * n + i] = cur;
            cur += (int)(pv & 0xffffu);
            od  += (int)(pv >> 16);
        }
        int id = cur - rp;
        out_norm[i] = rsqrtf((float)max(od, 1));
        in_norm[i]  = rsqrtf((float)max(id, 1));
    }
    if (i == 0) row_ptr[n] = E;
}

// ---- stage 4: scatter via LDS cursors --------------------------------------
__global__ __launch_bounds__(256)
void scatter_range(const int* __restrict__ src, const int* __restrict__ dst,
                   const float* __restrict__ ew, const float* __restrict__ out_norm,
                   const int* __restrict__ cb, int2* __restrict__ edges,
                   int E, int N) {
    __shared__ int cur[RSIZE];
    const int s = blockIdx.x;
    const int r = blockIdx.y;
    const int base = r << RBITS;
    const int t = threadIdx.x;
    for (int j = t; j < RSIZE; j += 256)
        if (base + j < N) cur[j] = cb[(size_t)s * N + base + j];
    __syncthreads();

    const int ech = (E + NSUB - 1) / NSUB;
    const int e0 = s * ech;
    const int e1 = min(E, e0 + ech);
    const int n4 = (e1 - e0) >> 2;
    for (int g = t; g < n4; g += 256) {
        int4 d4 = *reinterpret_cast<const int4*>(dst + e0 + g * 4);
        int4 s4 = *reinterpret_cast<const int4*>(src + e0 + g * 4);
        float4 w4 = *reinterpret_cast<const float4*>(ew + e0 + g * 4);
        #pragma unroll
        for (int j = 0; j < 4; ++j) {
            int d = (&d4.x)[j] - base;
            if ((unsigned)d < RSIZE) {
                int sv = (&s4.x)[j];
                int pos = atomicAdd(&cur[d], 1);
                float w = (&w4.x)[j] * out_norm[sv];
                edges[pos] = make_int2(sv, __float_as_int(w));
            }
        }
    }
    for (int e = e0 + n4 * 4 + t; e < e1; e += 256) {
        int d = dst[e] - base;
        if ((unsigned)d < RSIZE) {
            int sv = src[e];
            int pos = atomicAdd(&cur[d], 1);
            float w = ew[e] * out_norm[sv];
            edges[pos] = make_int2(sv, __float_as_int(w));
        }
    }
}

// ---- weight transpose + bf16 hi/lo split: W[K][128] -> Wt[n][k] ------------
__global__ __launch_bounds__(256)
void conv_w(const float* __restrict__ W, ushort* __restrict__ Wt_hi,
            ushort* __restrict__ Wt_lo, int K) {
    int i = blockIdx.x * 256 + threadIdx.x;
    if (i < K * 128) {
        int k = i >> 7, n = i & 127;
        float x = W[i];
        ushort hi = f2bf(x);
        ushort lo = f2bf(x - bf2f(hi));
        Wt_hi[(size_t)n * K + k] = hi;
        Wt_lo[(size_t)n * K + k] = lo;
    }
}

// ---- bf16x3 split MFMA GEMM: C[M x 128] = A[M x K] @ W[K x 128] ------------
template <int MODE>
__global__ __launch_bounds__(256)
void gemm128_mfma(const float* __restrict__ A, const ushort* __restrict__ Wt_hi,
                  const ushort* __restrict__ Wt_lo, float* __restrict__ C,
                  int M, int K,
                  const float* __restrict__ rownorm, const float* __restrict__ bias) {
    constexpr int BK = 32;
    constexpr int AP = 40;
    __shared__ __align__(16) ushort As_hi[64 * AP];
    __shared__ __align__(16) ushort As_lo[64 * AP];
    __shared__ __align__(16) ushort Bs_hi[128 * AP];
    __shared__ __align__(16) ushort Bs_lo[128 * AP];

    const int t = threadIdx.x;
    const int w = t >> 6;
    const int l = t & 63;
    const int row0 = blockIdx.x * 64;

    const int ar = t >> 2;
    const int ak = (t & 3) * 8;
    const int bn = t >> 1;
    const int bko = (t & 1) * 16;

    const int fr = l & 15;
    const int fk = (l >> 4) * 8;

    f32x4 acc[8];
    #pragma unroll
    for (int i = 0; i < 8; ++i) acc[i] = (f32x4){0.f, 0.f, 0.f, 0.f};

    const bool arow_ok = (row0 + ar < M);
    const float* ap = A + (size_t)(row0 + ar) * K;

    for (int k0 = 0; k0 < K; k0 += BK) {
        float av[8];
        if (arow_ok) {
            float4 f0 = *reinterpret_cast<const float4*>(ap + k0 + ak);
            float4 f1 = *reinterpret_cast<const float4*>(ap + k0 + ak + 4);
            av[0] = f0.x; av[1] = f0.y; av[2] = f0.z; av[3] = f0.w;
            av[4] = f1.x; av[5] = f1.y; av[6] = f1.z; av[7] = f1.w;
        } else {
            #pragma unroll
            for (int j = 0; j < 8; ++j) av[j] = 0.f;
        }
        bf16x8 ah, al;
        #pragma unroll
        for (int j = 0; j < 8; ++j) {
            ushort hi = f2bf(av[j]);
            ah[j] = (short)hi;
            al[j] = (short)f2bf(av[j] - bf2f(hi));
        }
        const ushort* wh = Wt_hi + (size_t)bn * K + k0 + bko;
        const ushort* wl = Wt_lo + (size_t)bn * K + k0 + bko;
        bf16x8 bh0 = *reinterpret_cast<const bf16x8*>(wh);
        bf16x8 bh1 = *reinterpret_cast<const bf16x8*>(wh + 8);
        bf16x8 bl0 = *reinterpret_cast<const bf16x8*>(wl);
        bf16x8 bl1 = *reinterpret_cast<const bf16x8*>(wl + 8);

        __syncthreads();
        *reinterpret_cast<bf16x8*>(As_hi + ar * AP + ak) = ah;
        *reinterpret_cast<bf16x8*>(As_lo + ar * AP + ak) = al;
        *reinterpret_cast<bf16x8*>(Bs_hi + bn * AP + bko)     = bh0;
        *reinterpret_cast<bf16x8*>(Bs_hi + bn * AP + bko + 8) = bh1;
        *reinterpret_cast<bf16x8*>(Bs_lo + bn * AP + bko)     = bl0;
        *reinterpret_cast<bf16x8*>(Bs_lo + bn * AP + bko + 8) = bl1;
        __syncthreads();

        bf16x8 a_hi = *reinterpret_cast<const bf16x8*>(As_hi + (w * 16 + fr) * AP + fk);
        bf16x8 a_lo = *reinterpret_cast<const bf16x8*>(As_lo + (w * 16 + fr) * AP + fk);
        #pragma unroll
        for (int nt = 0; nt < 8; ++nt) {
            bf16x8 b_hi = *reinterpret_cast<const bf16x8*>(Bs_hi + (nt * 16 + fr) * AP + fk);
            bf16x8 b_lo = *reinterpret_cast<const bf16x8*>(Bs_lo + (nt * 16 + fr) * AP + fk);
            acc[nt] = __builtin_amdgcn_mfma_f32_16x16x32_bf16(a_hi, b_hi, acc[nt], 0, 0, 0);
            acc[nt] = __builtin_amdgcn_mfma_f32_16x16x32_bf16(a_hi, b_lo, acc[nt], 0, 0, 0);
            acc[nt] = __builtin_amdgcn_mfma_f32_16x16x32_bf16(a_lo, b_hi, acc[nt], 0, 0, 0);
        }
    }

    float bb[8];
    if (MODE == 1) {
        #pragma unroll
        for (int nt = 0; nt < 8; ++nt) bb[nt] = bias[nt * 16 + fr];
    }
    #pragma unroll
    for (int r = 0; r < 4; ++r) {
        int row = row0 + w * 16 + (l >> 4) * 4 + r;
        if (row >= M) continue;
        float rn = (MODE == 1) ? rownorm[row] : 0.f;
        float* cp = C + (size_t)row * 128;
        #pragma unroll
        for (int nt = 0; nt < 8; ++nt) {
            float v = acc[nt][r];
            if (MODE == 1) v = fmaxf(fmaf(v, rn, bb[nt]), 0.f);
            cp[nt * 16 + fr] = v;
        }
    }
}

// ---- fp32 tiled GEMM (layer 3, Nn<=64; ldc padded): BM=64 BN=64 BK=16 ------
template <int MODE>
__global__ __launch_bounds__(256)
void gemm_f32(const float* __restrict__ A, const float* __restrict__ B,
              float* __restrict__ C, int M, int Nn, int K,
              int lda, int ldb, int ldc,
              const float* __restrict__ rownorm, const float* __restrict__ bias) {
    constexpr int BM = 64, BN = 64, BK = 16;
    __shared__ float As[BK][BM + 4];
    __shared__ float Bs[BK][BN];

    const int t = threadIdx.x;
    const int row0 = blockIdx.x * BM;
    const int col0 = blockIdx.y * BN;
    const int rowbase = (t >> 4) * 4;
    const int colbase = (t & 15) * 4;
    const int ar  = t >> 2;
    const int akq = (t & 3) * 4;
    const int bk  = t >> 4;
    const int bc4 = (t & 15) * 4;

    float acc[4][4];
    #pragma unroll
    for (int i = 0; i < 4; ++i)
        #pragma unroll
        for (int j = 0; j < 4; ++j) acc[i][j] = 0.f;

    const bool arow_ok = (row0 + ar < M);
    const bool bcol_ok = (col0 + bc4 < Nn);
    const float* ap = A + (size_t)(row0 + ar) * lda + akq;

    float4 a0 = make_float4(0.f, 0.f, 0.f, 0.f), bv = a0;
    if (arow_ok) a0 = *reinterpret_cast<const float4*>(ap);
    if (bcol_ok)
        bv = *reinterpret_cast<const float4*>(B + (size_t)bk * ldb + col0 + bc4);

    for (int k0 = 0; k0 < K; k0 += BK) {
        __syncthreads();
        As[akq + 0][ar] = a0.x;
        As[akq + 1][ar] = a0.y;
        As[akq + 2][ar] = a0.z;
        As[akq + 3][ar] = a0.w;
        *reinterpret_cast<float4*>(&Bs[bk][bc4]) = bv;
        __syncthreads();

        if (k0 + BK < K) {
            if (arow_ok) a0 = *reinterpret_cast<const float4*>(ap + k0 + BK);
            if (bcol_ok)
                bv = *reinterpret_cast<const float4*>(B + (size_t)(k0 + BK + bk) * ldb + col0 + bc4);
        }

        #pragma unroll
        for (int kk = 0; kk < BK; ++kk) {
            float4 av  = *reinterpret_cast<const float4*>(&As[kk][rowbase]);
            float4 bv2 = *reinterpret_cast<const float4*>(&Bs[kk][colbase]);
            float a[4] = {av.x, av.y, av.z, av.w};
            float b[4] = {bv2.x, bv2.y, bv2.z, bv2.w};
            #pragma unroll
            for (int i = 0; i < 4; ++i)
                #pragma unroll
                for (int j = 0; j < 4; ++j)
                    acc[i][j] = fmaf(a[i], b[j], acc[i][j]);
        }
    }

    if (col0 + colbase >= Nn) return;
    float4 bb = make_float4(0.f, 0.f, 0.f, 0.f);
    if (MODE == 1) bb = *reinterpret_cast<const float4*>(bias + col0 + colbase);
    #pragma unroll
    for (int i = 0; i < 4; ++i) {
        int row = row0 + rowbase + i;
        if (row >= M) break;
        float4 v = make_float4(acc[i][0], acc[i][1], acc[i][2], acc[i][3]);
        if (MODE == 1) {
            float rn = rownorm[row];
            v.x = fmaxf(fmaf(v.x, rn, bb.x), 0.f);
            v.y = fmaxf(fmaf(v.y, rn, bb.y), 0.f);
            v.z = fmaxf(fmaf(v.z, rn, bb.z), 0.f);
            v.w = fmaxf(fmaf(v.w, rn, bb.w), 0.f);
        }
        *reinterpret_cast<float4*>(C + (size_t)row * ldc + col0 + colbase) = v;
    }
}

// ---- SpMM (CSR by dst), 128 features: wave/node, 8-slot edge unroll --------
// Lane owns cols [2*lane, 2*lane+2). Per iter: 8 wave-uniform record loads
// (L1 broadcast) then 8 INDEPENDENT float2 gathers -> 4KB/wave in flight.
// Tail slots: col=0, w=0 (exact). Slot accumulators summed in fixed order.
template <int EPI>
__global__ __launch_bounds__(256)
void spmm128(const float* __restrict__ H, const int* __restrict__ row_ptr,
             const int2* __restrict__ edges,
             float* __restrict__ out, const float* __restrict__ in_norm,
             const float* __restrict__ bias, int n) {
    const int t = threadIdx.x;
    const int w = t >> 6;
    const int lane = t & 63;
    const int wid = blockIdx.x * 4 + w;
    if (wid >= n) return;
    const int e0 = row_ptr[wid], e1 = row_ptr[wid + 1];

    float2 acc[8];
    #pragma unroll
    for (int j = 0; j < 8; ++j) acc[j] = make_float2(0.f, 0.f);

    for (int e = e0; e < e1; e += 8) {
        int   cols[8];
        float wvs[8];
        #pragma unroll
        for (int j = 0; j < 8; ++j) {
            if (e + j < e1) {
                int2 er = edges[e + j];
                cols[j] = er.x;
                wvs[j]  = __int_as_float(er.y);
            } else {
                cols[j] = 0;
                wvs[j]  = 0.f;
            }
        }
        float2 v[8];
        #pragma unroll
        for (int j = 0; j < 8; ++j)
            v[j] = *reinterpret_cast<const float2*>(H + (size_t)cols[j] * 128 + lane * 2);
        #pragma unroll
        for (int j = 0; j < 8; ++j) {
            acc[j].x = fmaf(wvs[j], v[j].x, acc[j].x);
            acc[j].y = fmaf(wvs[j], v[j].y, acc[j].y);
        }
    }

    float2 r01 = make_float2(acc[0].x + acc[1].x, acc[0].y + acc[1].y);
    float2 r23 = make_float2(acc[2].x + acc[3].x, acc[2].y + acc[3].y);
    float2 r45 = make_float2(acc[4].x + acc[5].x, acc[4].y + acc[5].y);
    float2 r67 = make_float2(acc[6].x + acc[7].x, acc[6].y + acc[7].y);
    float2 r = make_float2((r01.x + r23.x) + (r45.x + r67.x),
                           (r01.y + r23.y) + (r45.y + r67.y));

    if (EPI == 1) {
        float nn = in_norm[wid];
        float2 bb = *reinterpret_cast<const float2*>(bias + lane * 2);
        r.x = fmaxf(fmaf(r.x, nn, bb.x), 0.f);
        r.y = fmaxf(fmaf(r.y, nn, bb.y), 0.f);
    }
    *reinterpret_cast<float2*>(out + (size_t)wid * 128 + lane * 2) = r;
}

// ---- SpMM final layer (T3 padded 64 cols; out N x 40): 8-slot unroll -------
__global__ __launch_bounds__(256)
void spmm40(const float* __restrict__ H, const int* __restrict__ row_ptr,
            const int2* __restrict__ edges,
            float* __restrict__ out, const float* __restrict__ in_norm,
            const float* __restrict__ bias, int n) {
    const int t = threadIdx.x;
    const int w = t >> 6;
    const int lane = t & 63;
    const int wid = blockIdx.x * 4 + w;
    if (wid >= n) return;
    const int e0 = row_ptr[wid], e1 = row_ptr[wid + 1];

    float acc[8];
    #pragma unroll
    for (int j = 0; j < 8; ++j) acc[j] = 0.f;

    for (int e = e0; e < e1; e += 8) {
        int   cols[8];
        float wvs[8];
        #pragma unroll
        for (int j = 0; j < 8; ++j) {
            if (e + j < e1) {
                int2 er = edges[e + j];
                cols[j] = er.x;
                wvs[j]  = __int_as_float(er.y);
            } else {
                cols[j] = 0;
                wvs[j]  = 0.f;
            }
        }
        float v[8];
        #pragma unroll
        for (int j = 0; j < 8; ++j)
            v[j] = H[(size_t)cols[j] * 64 + lane];
        #pragma unroll
        for (int j = 0; j < 8; ++j)
            acc[j] = fmaf(wvs[j], v[j], acc[j]);
    }

    float r = ((acc[0] + acc[1]) + (acc[2] + acc[3])) +
              ((acc[4] + acc[5]) + (acc[6] + acc[7]));

    if (lane < CDIM) {
        float nn = in_norm[wid];
        out[(size_t)wid * CDIM + lane] = fmaf(r, nn, bias[lane]);
    }
}

// ---------------------------------------------------------------------------

extern "C" void kernel_launch(void* const* d_in, const int* in_sizes, int n_in,
                              void* d_out, int out_size, void* d_ws, size_t ws_size,
                              hipStream_t stream) {
    const float* features = (const float*)d_in[0];
    const int*   src      = (const int*)d_in[1];
    const int*   dst      = (const int*)d_in[2];
    const float* ew       = (const float*)d_in[3];
    const float* W1       = (const float*)d_in[4];
    const float* b1       = (const float*)d_in[5];
    const float* W2       = (const float*)d_in[6];
    const float* b2       = (const float*)d_in[7];
    const float* W3       = (const float*)d_in[8];
    const float* b3       = (const float*)d_in[9];
    float* out = (float*)d_out;

    const int N = in_sizes[0] / F_IN;   // 50000
    const int E = in_sizes[1];          // 800000
    const int NR = (N + RSIZE - 1) >> RBITS;

    // ---- workspace carve-up ----
    char* ws = (char*)d_ws;
    size_t off = 0;
    auto alloc = [&](size_t bytes) -> void* {
        void* p = ws + off;
        off += (bytes + 255) & ~(size_t)255;
        return p;
    };
    int*    row_ptr  = (int*)alloc((size_t)(N + 1) * 4);
    float*  out_norm = (float*)alloc((size_t)N * 4);
    float*  in_norm  = (float*)alloc((size_t)N * 4);
    int2*   edges    = (int2*)alloc((size_t)E * 8);
    float*  B0       = (float*)alloc((size_t)N * HDIM * 4);
    float*  B1       = (float*)alloc((size_t)N * HDIM * 4);
    float*  B2       = (float*)alloc((size_t)N * HDIM * 4);
    const int nb     = (N + 1023) / 1024;
    int*    bsums    = (int*)alloc((size_t)nb * 4);
    ushort* Wt1_hi   = (ushort*)alloc((size_t)F_IN * 128 * 2);
    ushort* Wt1_lo   = (ushort*)alloc((size_t)F_IN * 128 * 2);
    ushort* Wt2_hi   = (ushort*)alloc((size_t)HDIM * 128 * 2);
    ushort* Wt2_lo   = (ushort*)alloc((size_t)HDIM * 128 * 2);
    int*    pc       = (int*)B0;
    int*    cb       = (int*)B1;
    (void)ws_size;

    // ---- preprocessing (no global atomics) + weight split ----
    {
        dim3 grid(NSUB, NR);
        histo_range<<<grid, 256, 0, stream>>>(src, dst, pc, E);
    }
    conv_w<<<(F_IN * 128 + 255) / 256, 256, 0, stream>>>(W1, Wt1_hi, Wt1_lo, F_IN);
    conv_w<<<(HDIM * 128 + 255) / 256, 256, 0, stream>>>(W2, Wt2_hi, Wt2_lo, HDIM);
    scan_blocks<<<nb, 256, 0, stream>>>(pc, row_ptr, bsums, N);
    scan_sums<<<1, 64, 0, stream>>>(bsums, nb);
    int ngrid = (N + 255) / 256;
    node_prep_kernel<<<ngrid, 256, 0, stream>>>(pc, row_ptr, bsums,
                                                out_norm, in_norm, cb, N, E);
    {
        dim3 grid(NSUB, NR);
        scatter_range<<<grid, 256, 0, stream>>>(src, dst, ew, out_norm, cb,
                                                edges, E, N);
    }

    const int spmm_grid = (N + 3) / 4;
    const int ggrid = (N + 63) / 64;

    // ---- layer 1: T1 = X @ W1 ; H1 = relu(SpMM(T1)*in_norm + b1) ----
    gemm128_mfma<0><<<ggrid, 256, 0, stream>>>(features, Wt1_hi, Wt1_lo, B0,
                                               N, F_IN, nullptr, nullptr);
    spmm128<1><<<spmm_grid, 256, 0, stream>>>(B0, row_ptr, edges, B1, in_norm, b1, N);

    // ---- layer 2: A2 = SpMM(H1) ; H2 = relu((A2 @ W2)*in_norm + b2) ----
    spmm128<0><<<spmm_grid, 256, 0, stream>>>(B1, row_ptr, edges, B2, nullptr, nullptr, N);
    gemm128_mfma<1><<<ggrid, 256, 0, stream>>>(B2, Wt2_hi, Wt2_lo, B0,
                                               N, HDIM, in_norm, b2);

    // ---- layer 3: T3 = H2 @ W3 (ldc=64 padded) ; OUT = SpMM(T3)*in_norm+b3 -
    {
        dim3 grid(ggrid, 1);
        gemm_f32<0><<<grid, 256, 0, stream>>>(B0, W3, B1, N, CDIM, HDIM,
                                              HDIM, CDIM, 64, nullptr, nullptr);
    }
    spmm40<<<spmm_grid, 256, 0, stream>>>(B1, row_ptr, edges, out, in_norm, b3, N);
}

// Round 16
// 249.769 us; speedup vs baseline: 1.2260x; 1.2260x over previous
//
#include <hip/hip_runtime.h>
#include <hip/hip_bf16.h>
#include <cstdint>

// ---------------------------------------------------------------------------
// GCN 3-layer forward. fp32 SpMM, bf16x3 split-MFMA GEMMs (layers 1-2).
// Round 16: revert SpMM to r12 form (fastest: 54us, 3.8TB/s; r13-r15
// restructures all regressed -> L3 service rate for random 512B reads is
// the binding constraint). T3 un-padded to 40 cols (160B rows): spmm40
// gather 256->160B/edge.
// ---------------------------------------------------------------------------

#define F_IN 256
#define HDIM 128
#define CDIM 40
#define RBITS 13
#define RSIZE 8192
#define NSUB 64

typedef short bf16x8 __attribute__((ext_vector_type(8)));
typedef float f32x4  __attribute__((ext_vector_type(4)));

__device__ __forceinline__ ushort f2bf(float x) {
    uint b = __float_as_uint(x);
    return (ushort)((b + 0x7fffu + ((b >> 16) & 1u)) >> 16);   // RNE
}
__device__ __forceinline__ float bf2f(ushort h) {
    return __uint_as_float(((uint)h) << 16);
}

// ---- stage 1: per-(range,subset) LDS histogram, packed in|out --------------
__global__ __launch_bounds__(256)
void histo_range(const int* __restrict__ src, const int* __restrict__ dst,
                 int* __restrict__ pc, int E) {
    __shared__ int h[RSIZE];
    const int s = blockIdx.x;
    const int r = blockIdx.y;
    const int base = r << RBITS;
    const int t = threadIdx.x;
    int4* h4 = reinterpret_cast<int4*>(h);
    for (int j = t; j < RSIZE / 4; j += 256) h4[j] = make_int4(0, 0, 0, 0);
    __syncthreads();

    const int ech = (E + NSUB - 1) / NSUB;
    const int e0 = s * ech;
    const int e1 = min(E, e0 + ech);
    const int n4 = (e1 - e0) >> 2;
    for (int g = t; g < n4; g += 256) {
        int4 d4 = *reinterpret_cast<const int4*>(dst + e0 + g * 4);
        int4 s4 = *reinterpret_cast<const int4*>(src + e0 + g * 4);
        #pragma unroll
        for (int j = 0; j < 4; ++j) {
            int d = (&d4.x)[j] - base;
            int v = (&s4.x)[j] - base;
            if ((unsigned)d < RSIZE) atomicAdd(&h[d], 1);
            if ((unsigned)v < RSIZE) atomicAdd(&h[v], 0x10000);
        }
    }
    for (int e = e0 + n4 * 4 + t; e < e1; e += 256) {
        int d = dst[e] - base, v = src[e] - base;
        if ((unsigned)d < RSIZE) atomicAdd(&h[d], 1);
        if ((unsigned)v < RSIZE) atomicAdd(&h[v], 0x10000);
    }
    __syncthreads();
    int* p = pc + ((size_t)r * NSUB + s) * RSIZE;
    for (int j = t; j < RSIZE; j += 256) p[j] = h[j];
}

// ---- stage 2: block-level exclusive scan of in-degree ----------------------
__global__ __launch_bounds__(256)
void scan_blocks(const int* __restrict__ pc, int* __restrict__ out,
                 int* __restrict__ bsums, int n) {
    const int t = threadIdx.x;
    const int idx = blockIdx.x * 1024 + t * 4;
    int4 v = make_int4(0, 0, 0, 0);
    if (idx + 3 < n) {
        const int r = idx >> RBITS, off = idx & (RSIZE - 1);
        const int* p = pc + (size_t)r * NSUB * RSIZE + off;
        #pragma unroll 8
        for (int c = 0; c < NSUB; ++c) {
            int4 u = *reinterpret_cast<const int4*>(p + (size_t)c * RSIZE);
            v.x += u.x & 0xffff; v.y += u.y & 0xffff;
            v.z += u.z & 0xffff; v.w += u.w & 0xffff;
        }
    } else {
        for (int j = 0; j < 4; ++j) {
            if (idx + j < n) {
                const int r = (idx + j) >> RBITS, off = (idx + j) & (RSIZE - 1);
                int s = 0;
                for (int c = 0; c < NSUB; ++c)
                    s += pc[(size_t)r * NSUB * RSIZE + (size_t)c * RSIZE + off] & 0xffff;
                (&v.x)[j] = s;
            }
        }
    }
    const int s = v.x + v.y + v.z + v.w;
    const int lane = t & 63;
    int incl = s;
    #pragma unroll
    for (int off = 1; off < 64; off <<= 1) {
        int u = __shfl_up(incl, off);
        if (lane >= off) incl += u;
    }
    __shared__ int wsum[4];
    if (lane == 63) wsum[t >> 6] = incl;
    __syncthreads();
    const int w = t >> 6;
    int woff = 0;
    if (w > 0) woff += wsum[0];
    if (w > 1) woff += wsum[1];
    if (w > 2) woff += wsum[2];
    const int excl = woff + incl - s;
    if (idx + 3 < n) {
        *reinterpret_cast<int4*>(out + idx) =
            make_int4(excl, excl + v.x, excl + v.x + v.y, excl + v.x + v.y + v.z);
    } else {
        if (idx     < n) out[idx]     = excl;
        if (idx + 1 < n) out[idx + 1] = excl + v.x;
        if (idx + 2 < n) out[idx + 2] = excl + v.x + v.y;
        if (idx + 3 < n) out[idx + 3] = excl + v.x + v.y + v.z;
    }
    if (t == 255) bsums[blockIdx.x] = woff + incl;
}

__global__ __launch_bounds__(64)
void scan_sums(int* __restrict__ bsums, int nb) {
    const int lane = threadIdx.x & 63;
    int carry = 0;
    for (int base = 0; base < nb; base += 64) {
        int v = (base + lane < nb) ? bsums[base + lane] : 0;
        int incl = v;
        #pragma unroll
        for (int off = 1; off < 64; off <<= 1) {
            int u = __shfl_up(incl, off);
            if (lane >= off) incl += u;
        }
        if (base + lane < nb) bsums[base + lane] = carry + incl - v;
        carry += __shfl(incl, 63);
    }
}

// ---- stage 3: finalize row_ptr, norms, per-subset cursor bases cb ----------
__global__ __launch_bounds__(256)
void node_prep_kernel(const int* __restrict__ pc,
                      int* __restrict__ row_ptr, const int* __restrict__ bsums,
                      float* __restrict__ out_norm, float* __restrict__ in_norm,
                      int* __restrict__ cb, int n, int E) {
    int i = blockIdx.x * 256 + threadIdx.x;
    if (i < n) {
        const int r = i >> RBITS, off = i & (RSIZE - 1);
        const int* p = pc + (size_t)r * NSUB * RSIZE + off;
        int rp = row_ptr[i] + bsums[i >> 10];
        row_ptr[i] = rp;
        int cur = rp;
        int od = 0;
        #pragma unroll 8
        for (int c = 0; c < NSUB; ++c) {
            unsigned pv = (unsigned)p[(size_t)c * RSIZE];
            cb[(size_t)c * n + i] = cur;
            cur += (int)(pv & 0xffffu);
            od  += (int)(pv >> 16);
        }
        int id = cur - rp;
        out_norm[i] = rsqrtf((float)max(od, 1));
        in_norm[i]  = rsqrtf((float)max(id, 1));
    }
    if (i == 0) row_ptr[n] = E;
}

// ---- stage 4: scatter via LDS cursors --------------------------------------
__global__ __launch_bounds__(256)
void scatter_range(const int* __restrict__ src, const int* __restrict__ dst,
                   const float* __restrict__ ew, const float* __restrict__ out_norm,
                   const int* __restrict__ cb, int2* __restrict__ edges,
                   int E, int N) {
    __shared__ int cur[RSIZE];
    const int s = blockIdx.x;
    const int r = blockIdx.y;
    const int base = r << RBITS;
    const int t = threadIdx.x;
    for (int j = t; j < RSIZE; j += 256)
        if (base + j < N) cur[j] = cb[(size_t)s * N + base + j];
    __syncthreads();

    const int ech = (E + NSUB - 1) / NSUB;
    const int e0 = s * ech;
    const int e1 = min(E, e0 + ech);
    const int n4 = (e1 - e0) >> 2;
    for (int g = t; g < n4; g += 256) {
        int4 d4 = *reinterpret_cast<const int4*>(dst + e0 + g * 4);
        int4 s4 = *reinterpret_cast<const int4*>(src + e0 + g * 4);
        float4 w4 = *reinterpret_cast<const float4*>(ew + e0 + g * 4);
        #pragma unroll
        for (int j = 0; j < 4; ++j) {
            int d = (&d4.x)[j] - base;
            if ((unsigned)d < RSIZE) {
                int sv = (&s4.x)[j];
                int pos = atomicAdd(&cur[d], 1);
                float w = (&w4.x)[j] * out_norm[sv];
                edges[pos] = make_int2(sv, __float_as_int(w));
            }
        }
    }
    for (int e = e0 + n4 * 4 + t; e < e1; e += 256) {
        int d = dst[e] - base;
        if ((unsigned)d < RSIZE) {
            int sv = src[e];
            int pos = atomicAdd(&cur[d], 1);
            float w = ew[e] * out_norm[sv];
            edges[pos] = make_int2(sv, __float_as_int(w));
        }
    }
}

// ---- weight transpose + bf16 hi/lo split: W[K][128] -> Wt[n][k] ------------
__global__ __launch_bounds__(256)
void conv_w(const float* __restrict__ W, ushort* __restrict__ Wt_hi,
            ushort* __restrict__ Wt_lo, int K) {
    int i = blockIdx.x * 256 + threadIdx.x;
    if (i < K * 128) {
        int k = i >> 7, n = i & 127;
        float x = W[i];
        ushort hi = f2bf(x);
        ushort lo = f2bf(x - bf2f(hi));
        Wt_hi[(size_t)n * K + k] = hi;
        Wt_lo[(size_t)n * K + k] = lo;
    }
}

// ---- bf16x3 split MFMA GEMM: C[M x 128] = A[M x K] @ W[K x 128] ------------
template <int MODE>
__global__ __launch_bounds__(256)
void gemm128_mfma(const float* __restrict__ A, const ushort* __restrict__ Wt_hi,
                  const ushort* __restrict__ Wt_lo, float* __restrict__ C,
                  int M, int K,
                  const float* __restrict__ rownorm, const float* __restrict__ bias) {
    constexpr int BK = 32;
    constexpr int AP = 40;
    __shared__ __align__(16) ushort As_hi[64 * AP];
    __shared__ __align__(16) ushort As_lo[64 * AP];
    __shared__ __align__(16) ushort Bs_hi[128 * AP];
    __shared__ __align__(16) ushort Bs_lo[128 * AP];

    const int t = threadIdx.x;
    const int w = t >> 6;
    const int l = t & 63;
    const int row0 = blockIdx.x * 64;

    const int ar = t >> 2;
    const int ak = (t & 3) * 8;
    const int bn = t >> 1;
    const int bko = (t & 1) * 16;

    const int fr = l & 15;
    const int fk = (l >> 4) * 8;

    f32x4 acc[8];
    #pragma unroll
    for (int i = 0; i < 8; ++i) acc[i] = (f32x4){0.f, 0.f, 0.f, 0.f};

    const bool arow_ok = (row0 + ar < M);
    const float* ap = A + (size_t)(row0 + ar) * K;

    for (int k0 = 0; k0 < K; k0 += BK) {
        float av[8];
        if (arow_ok) {
            float4 f0 = *reinterpret_cast<const float4*>(ap + k0 + ak);
            float4 f1 = *reinterpret_cast<const float4*>(ap + k0 + ak + 4);
            av[0] = f0.x; av[1] = f0.y; av[2] = f0.z; av[3] = f0.w;
            av[4] = f1.x; av[5] = f1.y; av[6] = f1.z; av[7] = f1.w;
        } else {
            #pragma unroll
            for (int j = 0; j < 8; ++j) av[j] = 0.f;
        }
        bf16x8 ah, al;
        #pragma unroll
        for (int j = 0; j < 8; ++j) {
            ushort hi = f2bf(av[j]);
            ah[j] = (short)hi;
            al[j] = (short)f2bf(av[j] - bf2f(hi));
        }
        const ushort* wh = Wt_hi + (size_t)bn * K + k0 + bko;
        const ushort* wl = Wt_lo + (size_t)bn * K + k0 + bko;
        bf16x8 bh0 = *reinterpret_cast<const bf16x8*>(wh);
        bf16x8 bh1 = *reinterpret_cast<const bf16x8*>(wh + 8);
        bf16x8 bl0 = *reinterpret_cast<const bf16x8*>(wl);
        bf16x8 bl1 = *reinterpret_cast<const bf16x8*>(wl + 8);

        __syncthreads();
        *reinterpret_cast<bf16x8*>(As_hi + ar * AP + ak) = ah;
        *reinterpret_cast<bf16x8*>(As_lo + ar * AP + ak) = al;
        *reinterpret_cast<bf16x8*>(Bs_hi + bn * AP + bko)     = bh0;
        *reinterpret_cast<bf16x8*>(Bs_hi + bn * AP + bko + 8) = bh1;
        *reinterpret_cast<bf16x8*>(Bs_lo + bn * AP + bko)     = bl0;
        *reinterpret_cast<bf16x8*>(Bs_lo + bn * AP + bko + 8) = bl1;
        __syncthreads();

        bf16x8 a_hi = *reinterpret_cast<const bf16x8*>(As_hi + (w * 16 + fr) * AP + fk);
        bf16x8 a_lo = *reinterpret_cast<const bf16x8*>(As_lo + (w * 16 + fr) * AP + fk);
        #pragma unroll
        for (int nt = 0; nt < 8; ++nt) {
            bf16x8 b_hi = *reinterpret_cast<const bf16x8*>(Bs_hi + (nt * 16 + fr) * AP + fk);
            bf16x8 b_lo = *reinterpret_cast<const bf16x8*>(Bs_lo + (nt * 16 + fr) * AP + fk);
            acc[nt] = __builtin_amdgcn_mfma_f32_16x16x32_bf16(a_hi, b_hi, acc[nt], 0, 0, 0);
            acc[nt] = __builtin_amdgcn_mfma_f32_16x16x32_bf16(a_hi, b_lo, acc[nt], 0, 0, 0);
            acc[nt] = __builtin_amdgcn_mfma_f32_16x16x32_bf16(a_lo, b_hi, acc[nt], 0, 0, 0);
        }
    }

    float bb[8];
    if (MODE == 1) {
        #pragma unroll
        for (int nt = 0; nt < 8; ++nt) bb[nt] = bias[nt * 16 + fr];
    }
    #pragma unroll
    for (int r = 0; r < 4; ++r) {
        int row = row0 + w * 16 + (l >> 4) * 4 + r;
        if (row >= M) continue;
        float rn = (MODE == 1) ? rownorm[row] : 0.f;
        float* cp = C + (size_t)row * 128;
        #pragma unroll
        for (int nt = 0; nt < 8; ++nt) {
            float v = acc[nt][r];
            if (MODE == 1) v = fmaxf(fmaf(v, rn, bb[nt]), 0.f);
            cp[nt * 16 + fr] = v;
        }
    }
}

// ---- fp32 tiled GEMM (layer 3, Nn<=64; ldc arbitrary): BM=64 BN=64 BK=16 ---
template <int MODE>
__global__ __launch_bounds__(256)
void gemm_f32(const float* __restrict__ A, const float* __restrict__ B,
              float* __restrict__ C, int M, int Nn, int K,
              int lda, int ldb, int ldc,
              const float* __restrict__ rownorm, const float* __restrict__ bias) {
    constexpr int BM = 64, BN = 64, BK = 16;
    __shared__ float As[BK][BM + 4];
    __shared__ float Bs[BK][BN];

    const int t = threadIdx.x;
    const int row0 = blockIdx.x * BM;
    const int col0 = blockIdx.y * BN;
    const int rowbase = (t >> 4) * 4;
    const int colbase = (t & 15) * 4;
    const int ar  = t >> 2;
    const int akq = (t & 3) * 4;
    const int bk  = t >> 4;
    const int bc4 = (t & 15) * 4;

    float acc[4][4];
    #pragma unroll
    for (int i = 0; i < 4; ++i)
        #pragma unroll
        for (int j = 0; j < 4; ++j) acc[i][j] = 0.f;

    const bool arow_ok = (row0 + ar < M);
    const bool bcol_ok = (col0 + bc4 < Nn);
    const float* ap = A + (size_t)(row0 + ar) * lda + akq;

    float4 a0 = make_float4(0.f, 0.f, 0.f, 0.f), bv = a0;
    if (arow_ok) a0 = *reinterpret_cast<const float4*>(ap);
    if (bcol_ok)
        bv = *reinterpret_cast<const float4*>(B + (size_t)bk * ldb + col0 + bc4);

    for (int k0 = 0; k0 < K; k0 += BK) {
        __syncthreads();
        As[akq + 0][ar] = a0.x;
        As[akq + 1][ar] = a0.y;
        As[akq + 2][ar] = a0.z;
        As[akq + 3][ar] = a0.w;
        *reinterpret_cast<float4*>(&Bs[bk][bc4]) = bv;
        __syncthreads();

        if (k0 + BK < K) {
            if (arow_ok) a0 = *reinterpret_cast<const float4*>(ap + k0 + BK);
            if (bcol_ok)
                bv = *reinterpret_cast<const float4*>(B + (size_t)(k0 + BK + bk) * ldb + col0 + bc4);
        }

        #pragma unroll
        for (int kk = 0; kk < BK; ++kk) {
            float4 av  = *reinterpret_cast<const float4*>(&As[kk][rowbase]);
            float4 bv2 = *reinterpret_cast<const float4*>(&Bs[kk][colbase]);
            float a[4] = {av.x, av.y, av.z, av.w};
            float b[4] = {bv2.x, bv2.y, bv2.z, bv2.w};
            #pragma unroll
            for (int i = 0; i < 4; ++i)
                #pragma unroll
                for (int j = 0; j < 4; ++j)
                    acc[i][j] = fmaf(a[i], b[j], acc[i][j]);
        }
    }

    if (col0 + colbase >= Nn) return;
    float4 bb = make_float4(0.f, 0.f, 0.f, 0.f);
    if (MODE == 1) bb = *reinterpret_cast<const float4*>(bias + col0 + colbase);
    #pragma unroll
    for (int i = 0; i < 4; ++i) {
        int row = row0 + rowbase + i;
        if (row >= M) break;
        float4 v = make_float4(acc[i][0], acc[i][1], acc[i][2], acc[i][3]);
        if (MODE == 1) {
            float rn = rownorm[row];
            v.x = fmaxf(fmaf(v.x, rn, bb.x), 0.f);
            v.y = fmaxf(fmaf(v.y, rn, bb.y), 0.f);
            v.z = fmaxf(fmaf(v.z, rn, bb.z), 0.f);
            v.w = fmaxf(fmaf(v.w, rn, bb.w), 0.f);
        }
        *reinterpret_cast<float4*>(C + (size_t)row * ldc + col0 + colbase) = v;
    }
}

// ---- SpMM (CSR by dst), 128 features: r12 form (4x16-lane edge streams) ----
template <int EPI>
__global__ __launch_bounds__(256)
void spmm128(const float* __restrict__ H, const int* __restrict__ row_ptr,
             const int2* __restrict__ edges,
             float* __restrict__ out, const float* __restrict__ in_norm,
             const float* __restrict__ bias, int n) {
    int wid  = (blockIdx.x * 256 + threadIdx.x) >> 6;
    int lane = threadIdx.x & 63;
    if (wid >= n) return;
    const int quarter = lane >> 4;
    const int q       = lane & 15;
    int e0 = row_ptr[wid], e1 = row_ptr[wid + 1];
    float4 acc0 = make_float4(0.f, 0.f, 0.f, 0.f);
    float4 acc1 = make_float4(0.f, 0.f, 0.f, 0.f);
    #pragma unroll 2
    for (int e = e0 + quarter; e < e1; e += 4) {
        int2 er = edges[e];
        int   s = er.x;
        float w = __int_as_float(er.y);
        const float* hp = H + (size_t)s * 128 + q * 4;
        float4 v0 = *reinterpret_cast<const float4*>(hp);
        float4 v1 = *reinterpret_cast<const float4*>(hp + 64);
        acc0.x = fmaf(w, v0.x, acc0.x); acc0.y = fmaf(w, v0.y, acc0.y);
        acc0.z = fmaf(w, v0.z, acc0.z); acc0.w = fmaf(w, v0.w, acc0.w);
        acc1.x = fmaf(w, v1.x, acc1.x); acc1.y = fmaf(w, v1.y, acc1.y);
        acc1.z = fmaf(w, v1.z, acc1.z); acc1.w = fmaf(w, v1.w, acc1.w);
    }
    #pragma unroll
    for (int d = 16; d <= 32; d <<= 1) {
        acc0.x += __shfl_xor(acc0.x, d); acc0.y += __shfl_xor(acc0.y, d);
        acc0.z += __shfl_xor(acc0.z, d); acc0.w += __shfl_xor(acc0.w, d);
        acc1.x += __shfl_xor(acc1.x, d); acc1.y += __shfl_xor(acc1.y, d);
        acc1.z += __shfl_xor(acc1.z, d); acc1.w += __shfl_xor(acc1.w, d);
    }
    if (quarter == 0) {
        if (EPI == 1) {
            float nn = in_norm[wid];
            float4 bb0 = *reinterpret_cast<const float4*>(bias + q * 4);
            float4 bb1 = *reinterpret_cast<const float4*>(bias + 64 + q * 4);
            acc0.x = fmaxf(fmaf(acc0.x, nn, bb0.x), 0.f);
            acc0.y = fmaxf(fmaf(acc0.y, nn, bb0.y), 0.f);
            acc0.z = fmaxf(fmaf(acc0.z, nn, bb0.z), 0.f);
            acc0.w = fmaxf(fmaf(acc0.w, nn, bb0.w), 0.f);
            acc1.x = fmaxf(fmaf(acc1.x, nn, bb1.x), 0.f);
            acc1.y = fmaxf(fmaf(acc1.y, nn, bb1.y), 0.f);
            acc1.z = fmaxf(fmaf(acc1.z, nn, bb1.z), 0.f);
            acc1.w = fmaxf(fmaf(acc1.w, nn, bb1.w), 0.f);
        }
        float* op = out + (size_t)wid * 128 + q * 4;
        *reinterpret_cast<float4*>(op)      = acc0;
        *reinterpret_cast<float4*>(op + 64) = acc1;
    }
}

// ---- SpMM final layer: T3 rows 40 floats (160B); out N x 40 ----------------
// r12 quarter-stream form; lanes q>=10 gather in-bounds garbage (within the
// oversized T3 buffer) that never crosses the q-preserving shuffle reduce.
__global__ __launch_bounds__(256)
void spmm40(const float* __restrict__ H, const int* __restrict__ row_ptr,
            const int2* __restrict__ edges,
            float* __restrict__ out, const float* __restrict__ in_norm,
            const float* __restrict__ bias, int n) {
    int wid  = (blockIdx.x * 256 + threadIdx.x) >> 6;
    int lane = threadIdx.x & 63;
    if (wid >= n) return;
    const int quarter = lane >> 4;
    const int q       = lane & 15;
    int e0 = row_ptr[wid], e1 = row_ptr[wid + 1];
    float4 acc = make_float4(0.f, 0.f, 0.f, 0.f);
    #pragma unroll 2
    for (int e = e0 + quarter; e < e1; e += 4) {
        int2 er = edges[e];
        int   s = er.x;
        float w = __int_as_float(er.y);
        float4 v = *reinterpret_cast<const float4*>(H + (size_t)s * 40 + q * 4);
        acc.x = fmaf(w, v.x, acc.x);
        acc.y = fmaf(w, v.y, acc.y);
        acc.z = fmaf(w, v.z, acc.z);
        acc.w = fmaf(w, v.w, acc.w);
    }
    #pragma unroll
    for (int d = 16; d <= 32; d <<= 1) {
        acc.x += __shfl_xor(acc.x, d);
        acc.y += __shfl_xor(acc.y, d);
        acc.z += __shfl_xor(acc.z, d);
        acc.w += __shfl_xor(acc.w, d);
    }
    if (quarter == 0 && q * 4 < CDIM) {
        float nn = in_norm[wid];
        float4 bb = *reinterpret_cast<const float4*>(bias + q * 4);
        acc.x = fmaf(acc.x, nn, bb.x);
        acc.y = fmaf(acc.y, nn, bb.y);
        acc.z = fmaf(acc.z, nn, bb.z);
        acc.w = fmaf(acc.w, nn, bb.w);
        *reinterpret_cast<float4*>(out + (size_t)wid * CDIM + q * 4) = acc;
    }
}

// ---------------------------------------------------------------------------

extern "C" void kernel_launch(void* const* d_in, const int* in_sizes, int n_in,
                              void* d_out, int out_size, void* d_ws, size_t ws_size,
                              hipStream_t stream) {
    const float* features = (const float*)d_in[0];
    const int*   src      = (const int*)d_in[1];
    const int*   dst      = (const int*)d_in[2];
    const float* ew       = (const float*)d_in[3];
    const float* W1       = (const float*)d_in[4];
    const float* b1       = (const float*)d_in[5];
    const float* W2       = (const float*)d_in[6];
    const float* b2       = (const float*)d_in[7];
    const float* W3       = (const float*)d_in[8];
    const float* b3       = (const float*)d_in[9];
    float* out = (float*)d_out;

    const int N = in_sizes[0] / F_IN;   // 50000
    const int E = in_sizes[1];          // 800000
    const int NR = (N + RSIZE - 1) >> RBITS;

    // ---- workspace carve-up ----
    char* ws = (char*)d_ws;
    size_t off = 0;
    auto alloc = [&](size_t bytes) -> void* {
        void* p = ws + off;
        off += (bytes + 255) & ~(size_t)255;
        return p;
    };
    int*    row_ptr  = (int*)alloc((size_t)(N + 1) * 4);
    float*  out_norm = (float*)alloc((size_t)N * 4);
    float*  in_norm  = (float*)alloc((size_t)N * 4);
    int2*   edges    = (int2*)alloc((size_t)E * 8);
    float*  B0       = (float*)alloc((size_t)N * HDIM * 4);
    float*  B1       = (float*)alloc((size_t)N * HDIM * 4);
    float*  B2       = (float*)alloc((size_t)N * HDIM * 4);
    const int nb     = (N + 1023) / 1024;
    int*    bsums    = (int*)alloc((size_t)nb * 4);
    ushort* Wt1_hi   = (ushort*)alloc((size_t)F_IN * 128 * 2);
    ushort* Wt1_lo   = (ushort*)alloc((size_t)F_IN * 128 * 2);
    ushort* Wt2_hi   = (ushort*)alloc((size_t)HDIM * 128 * 2);
    ushort* Wt2_lo   = (ushort*)alloc((size_t)HDIM * 128 * 2);
    int*    pc       = (int*)B0;
    int*    cb       = (int*)B1;
    (void)ws_size;

    // ---- preprocessing (no global atomics) + weight split ----
    {
        dim3 grid(NSUB, NR);
        histo_range<<<grid, 256, 0, stream>>>(src, dst, pc, E);
    }
    conv_w<<<(F_IN * 128 + 255) / 256, 256, 0, stream>>>(W1, Wt1_hi, Wt1_lo, F_IN);
    conv_w<<<(HDIM * 128 + 255) / 256, 256, 0, stream>>>(W2, Wt2_hi, Wt2_lo, HDIM);
    scan_blocks<<<nb, 256, 0, stream>>>(pc, row_ptr, bsums, N);
    scan_sums<<<1, 64, 0, stream>>>(bsums, nb);
    int ngrid = (N + 255) / 256;
    node_prep_kernel<<<ngrid, 256, 0, stream>>>(pc, row_ptr, bsums,
                                                out_norm, in_norm, cb, N, E);
    {
        dim3 grid(NSUB, NR);
        scatter_range<<<grid, 256, 0, stream>>>(src, dst, ew, out_norm, cb,
                                                edges, E, N);
    }

    const int spmm_grid = (N + 3) / 4;
    const int ggrid = (N + 63) / 64;

    // ---- layer 1: T1 = X @ W1 ; H1 = relu(SpMM(T1)*in_norm + b1) ----
    gemm128_mfma<0><<<ggrid, 256, 0, stream>>>(features, Wt1_hi, Wt1_lo, B0,
                                               N, F_IN, nullptr, nullptr);
    spmm128<1><<<spmm_grid, 256, 0, stream>>>(B0, row_ptr, edges, B1, in_norm, b1, N);

    // ---- layer 2: A2 = SpMM(H1) ; H2 = relu((A2 @ W2)*in_norm + b2) ----
    spmm128<0><<<spmm_grid, 256, 0, stream>>>(B1, row_ptr, edges, B2, nullptr, nullptr, N);
    gemm128_mfma<1><<<ggrid, 256, 0, stream>>>(B2, Wt2_hi, Wt2_lo, B0,
                                               N, HDIM, in_norm, b2);

    // ---- layer 3: T3 = H2 @ W3 (ldc=40) ; OUT = SpMM(T3)*in_norm + b3 ----
    {
        dim3 grid(ggrid, 1);
        gemm_f32<0><<<grid, 256, 0, stream>>>(B0, W3, B1, N, CDIM, HDIM,
                                              HDIM, CDIM, 40, nullptr, nullptr);
    }
    spmm40<<<spmm_grid, 256, 0, stream>>>(B1, row_ptr, edges, out, in_norm, b3, N);
}